// Round 3
// baseline (734.959 us; speedup 1.0000x reference)
//
#include <hip/hip_runtime.h>

// QuantizedLinear: out[8,8192] = x[8,8192] @ W^T, W = dequant4(qweight, scale, zero)
// qweight packed 2 nibbles/byte (low first), delivered as int32 (one 0..255 per int).
// GROUP=128 -> 64 packed ints per group.
//
// Each wave owns RPW=4 output rows and one K-quarter (KS=4, atomicAdd into
// pre-zeroed d_out). Grid = 2048 blocks = 8 blocks/CU -> full wave slots.
// Per iteration a lane loads int4 (4 packed ints = 8 k); 64 lanes cover
// 256 packed = 512 k = 4 quant groups. Lane's group = g4*4 + (lane>>4).

constexpr int M      = 8;
constexpr int OUTF   = 8192;
constexpr int INF    = 8192;
constexpr int NGROUP = 64;            // IN / GROUP
constexpr int PK4ROW = INF / 8;       // 1024 int4 per output row
constexpr int RPW    = 4;             // rows per wave
constexpr int WPB    = 4;             // waves per block (256 threads)
constexpr int KS     = 4;             // K splits
constexpr int NITER  = 16 / KS;       // dwordx4-iterations per K-slice (4)

__global__ __launch_bounds__(256, 8) void qlin4_kernel(
    const float* __restrict__ x,      // [8, 8192]
    const int*   __restrict__ qw,     // [8192, 4096] values 0..255
    const float* __restrict__ scale,  // [8192, 64]
    const float* __restrict__ zero,   // [8192, 64]
    float*       __restrict__ out)    // [8, 8192] (pre-zeroed; atomicAdd)
{
    const int lane = threadIdx.x & 63;
    const int wave = threadIdx.x >> 6;
    const int bid  = blockIdx.x;
    const int ks   = bid >> 9;                       // 0..3 (grid = 2048)
    const int n0   = (bid & 511) * (WPB * RPW) + wave * RPW;

    float acc[M][RPW];
    #pragma unroll
    for (int m = 0; m < M; ++m)
        #pragma unroll
        for (int r = 0; r < RPW; ++r) acc[m][r] = 0.0f;

    const int4*   __restrict__ qw4 = reinterpret_cast<const int4*>(qw);
    const float4* __restrict__ x4  = reinterpret_cast<const float4*>(x);  // [8][2048]

    #pragma unroll
    for (int t = 0; t < NITER; ++t) {
        const int g4 = ks * NITER + t;               // which 512-k chunk

        // Weights: lane covers packed ints [g4*256 + 4*lane .. +3] of each row.
        int4 q[RPW];
        #pragma unroll
        for (int r = 0; r < RPW; ++r)
            q[r] = qw4[(size_t)(n0 + r) * PK4ROW + (g4 * 64 + lane)];

        // This lane's quant group within the 4-group chunk.
        const int gidx = g4 * 4 + (lane >> 4);
        float s[RPW], zs[RPW];
        #pragma unroll
        for (int r = 0; r < RPW; ++r) {
            const float sc = scale[(n0 + r) * NGROUP + gidx];
            s[r]  = sc;
            zs[r] = zero[(n0 + r) * NGROUP + gidx] * sc;
        }

        // Dequant 8 k-values per row: w[2i] = low nibble of int i, w[2i+1] = high.
        float w[RPW][8];
        #pragma unroll
        for (int r = 0; r < RPW; ++r) {
            const int* qi = reinterpret_cast<const int*>(&q[r]);
            #pragma unroll
            for (int i = 0; i < 4; ++i) {
                w[r][2 * i]     = fmaf((float)(qi[i] & 15),        s[r], -zs[r]);
                w[r][2 * i + 1] = fmaf((float)((qi[i] >> 4) & 15), s[r], -zs[r]);
            }
        }

        // x: lane covers k = g4*512 + 8*lane .. +7  -> two float4 per m.
        #pragma unroll
        for (int m = 0; m < M; ++m) {
            const float4 xa = x4[m * (INF / 4) + g4 * 128 + 2 * lane];
            const float4 xb = x4[m * (INF / 4) + g4 * 128 + 2 * lane + 1];
            #pragma unroll
            for (int r = 0; r < RPW; ++r) {
                float a = acc[m][r];
                a = fmaf(w[r][0], xa.x, a);
                a = fmaf(w[r][1], xa.y, a);
                a = fmaf(w[r][2], xa.z, a);
                a = fmaf(w[r][3], xa.w, a);
                a = fmaf(w[r][4], xb.x, a);
                a = fmaf(w[r][5], xb.y, a);
                a = fmaf(w[r][6], xb.z, a);
                a = fmaf(w[r][7], xb.w, a);
                acc[m][r] = a;
            }
        }
    }

    // Wave-wide butterfly reduction; one atomicAdd per (m, r).
    #pragma unroll
    for (int m = 0; m < M; ++m) {
        #pragma unroll
        for (int r = 0; r < RPW; ++r) {
            float v = acc[m][r];
            #pragma unroll
            for (int off = 32; off > 0; off >>= 1)
                v += __shfl_xor(v, off, 64);
            if (lane == 0)
                atomicAdd(&out[m * OUTF + (n0 + r)], v);
        }
    }
}

extern "C" void kernel_launch(void* const* d_in, const int* in_sizes, int n_in,
                              void* d_out, int out_size, void* d_ws, size_t ws_size,
                              hipStream_t stream) {
    const float* x     = (const float*)d_in[0];
    const int*   qw    = (const int*)d_in[1];
    const float* scale = (const float*)d_in[2];
    const float* zero  = (const float*)d_in[3];
    float*       out   = (float*)d_out;

    hipMemsetAsync(out, 0, (size_t)M * OUTF * sizeof(float), stream);

    const int blocks = (OUTF / (WPB * RPW)) * KS;  // 512 * 4 = 2048
    qlin4_kernel<<<blocks, 256, 0, stream>>>(x, qw, scale, zero, out);
}

// Round 4
// 65.223 us; speedup vs baseline: 11.2685x; 11.2685x over previous
//
#include <hip/hip_runtime.h>

// QuantizedLinear: out[8,8192] = x[8,8192] @ W^T, W = dequant4(qweight, scale, zero)
// qweight packed 2 nibbles/byte (low first), delivered as int32 (one 0..255 per int).
// GROUP=128 -> 64 packed ints per group.
//
// Each wave owns RPW=4 output rows and one K-quarter (KS=4, atomicAdd into
// pre-zeroed d_out). Grid = 2048 blocks x 4 waves = 8192 waves = full chip
// wave capacity IF VGPR <= 64. R3 lesson: launch_bounds(256,8) forced
// VGPR=32 -> 800MB of scratch spills -> 12x regression. So: bounds(256,4)
// (allocator cap 128, HW still runs 8 waves/SIMD at VGPR<=64) and
// #pragma unroll 1 on the K loop to keep the live set ~52 VGPR.

constexpr int M      = 8;
constexpr int OUTF   = 8192;
constexpr int INF    = 8192;
constexpr int NGROUP = 64;            // IN / GROUP
constexpr int PK4ROW = INF / 8;       // 1024 int4 per output row
constexpr int RPW    = 4;             // rows per wave
constexpr int WPB    = 4;             // waves per block (256 threads)
constexpr int KS     = 4;             // K splits
constexpr int NITER  = 16 / KS;       // dwordx4-iterations per K-slice (4)

__global__ __launch_bounds__(256, 4) void qlin4_kernel(
    const float* __restrict__ x,      // [8, 8192]
    const int*   __restrict__ qw,     // [8192, 4096] values 0..255
    const float* __restrict__ scale,  // [8192, 64]
    const float* __restrict__ zero,   // [8192, 64]
    float*       __restrict__ out)    // [8, 8192] (pre-zeroed; atomicAdd)
{
    const int lane = threadIdx.x & 63;
    const int wave = threadIdx.x >> 6;
    const int bid  = blockIdx.x;
    const int ks   = bid >> 9;                       // 0..3 (grid = 2048)
    const int n0   = (bid & 511) * (WPB * RPW) + wave * RPW;

    float acc[M][RPW];
    #pragma unroll
    for (int m = 0; m < M; ++m)
        #pragma unroll
        for (int r = 0; r < RPW; ++r) acc[m][r] = 0.0f;

    const int4*   __restrict__ qw4 = reinterpret_cast<const int4*>(qw);
    const float4* __restrict__ x4  = reinterpret_cast<const float4*>(x);  // [8][2048]

    #pragma unroll 1
    for (int t = 0; t < NITER; ++t) {
        const int g4 = ks * NITER + t;               // which 512-k chunk

        // Weights: lane covers packed ints [g4*256 + 4*lane .. +3] of each row.
        int4 q[RPW];
        #pragma unroll
        for (int r = 0; r < RPW; ++r)
            q[r] = qw4[(size_t)(n0 + r) * PK4ROW + (g4 * 64 + lane)];

        // This lane's quant group within the 4-group chunk.
        const int gidx = g4 * 4 + (lane >> 4);
        float s[RPW], zs[RPW];
        #pragma unroll
        for (int r = 0; r < RPW; ++r) {
            const float sc = scale[(n0 + r) * NGROUP + gidx];
            s[r]  = sc;
            zs[r] = zero[(n0 + r) * NGROUP + gidx] * sc;
        }

        // Dequant 8 k-values per row: w[2i] = low nibble of int i, w[2i+1] = high.
        float w[RPW][8];
        #pragma unroll
        for (int r = 0; r < RPW; ++r) {
            const int* qi = reinterpret_cast<const int*>(&q[r]);
            #pragma unroll
            for (int i = 0; i < 4; ++i) {
                w[r][2 * i]     = fmaf((float)(qi[i] & 15),        s[r], -zs[r]);
                w[r][2 * i + 1] = fmaf((float)((qi[i] >> 4) & 15), s[r], -zs[r]);
            }
        }

        // x: lane covers k = g4*512 + 8*lane .. +7  -> two float4 per m.
        #pragma unroll
        for (int m = 0; m < M; ++m) {
            const float4 xa = x4[m * (INF / 4) + g4 * 128 + 2 * lane];
            const float4 xb = x4[m * (INF / 4) + g4 * 128 + 2 * lane + 1];
            #pragma unroll
            for (int r = 0; r < RPW; ++r) {
                float a = acc[m][r];
                a = fmaf(w[r][0], xa.x, a);
                a = fmaf(w[r][1], xa.y, a);
                a = fmaf(w[r][2], xa.z, a);
                a = fmaf(w[r][3], xa.w, a);
                a = fmaf(w[r][4], xb.x, a);
                a = fmaf(w[r][5], xb.y, a);
                a = fmaf(w[r][6], xb.z, a);
                a = fmaf(w[r][7], xb.w, a);
                acc[m][r] = a;
            }
        }
    }

    // Wave-wide butterfly reduction; one atomicAdd per (m, r).
    #pragma unroll
    for (int m = 0; m < M; ++m) {
        #pragma unroll
        for (int r = 0; r < RPW; ++r) {
            float v = acc[m][r];
            #pragma unroll
            for (int off = 32; off > 0; off >>= 1)
                v += __shfl_xor(v, off, 64);
            if (lane == 0)
                atomicAdd(&out[m * OUTF + (n0 + r)], v);
        }
    }
}

extern "C" void kernel_launch(void* const* d_in, const int* in_sizes, int n_in,
                              void* d_out, int out_size, void* d_ws, size_t ws_size,
                              hipStream_t stream) {
    const float* x     = (const float*)d_in[0];
    const int*   qw    = (const int*)d_in[1];
    const float* scale = (const float*)d_in[2];
    const float* zero  = (const float*)d_in[3];
    float*       out   = (float*)d_out;

    hipMemsetAsync(out, 0, (size_t)M * OUTF * sizeof(float), stream);

    const int blocks = (OUTF / (WPB * RPW)) * KS;  // 512 * 4 = 2048
    qlin4_kernel<<<blocks, 256, 0, stream>>>(x, qw, scale, zero, out);
}

// Round 6
// 57.115 us; speedup vs baseline: 12.8682x; 1.1420x over previous
//
#include <hip/hip_runtime.h>

// out[8,8192] = x[8,8192] @ W^T, W = dequant4(qweight, scale, zero), GROUP=128.
// qweight: 2 nibbles/byte (low first), delivered as int32 (one 0..255 per int).
//
// R6 structure: block = 512 thr (8 waves), owns 32 output rows x one K-quarter.
//  - x K-slice (8 m x 2048 k = 64KB) staged once into LDS with involution
//    swizzle swz(S) = S ^ ((S>>4)&7). R5 bug fixed: read BOTH float4s via
//    explicit swz (xs[swz(S)], xs[swz(S+1)]) -- no P+1 shortcut, no OOB.
//  - scale/zero*scale preloaded per wave (64 lanes = 4 rows x 16 groups),
//    redistributed in-loop with __shfl. Exact dequant (cvt + fma), no
//    2^23 magic (R5 lesson: its group-coherent rounding error ~1.0 absmax).
//  - weight loads are the only in-loop vmem: 4x dwordx4/iter, 2-deep prefetch.
//  - k-chunk processed in two halves (q.xy->xa, q.zw->xb) to keep peak
//    VGPR ~100; launch_bounds(512,4) caps at 128 (above need -> no spill).

constexpr int M      = 8;
constexpr int OUTF   = 8192;
constexpr int INF    = 8192;
constexpr int NG     = 64;            // groups per row
constexpr int KS     = 4;             // K splits
constexpr int KSLICE = INF / KS;      // 2048 k per block
constexpr int WPB    = 8;             // waves per block (512 threads)
constexpr int RPW    = 4;             // rows per wave
constexpr int ROWS   = WPB * RPW;     // 32 rows per block
constexpr int NIT    = KSLICE / 512;  // 4 k-chunks of 512 per slice
constexpr int PK4ROW = INF / 8;       // 1024 int4 per weight row

__device__ __forceinline__ int swz(int S) { return S ^ ((S >> 4) & 7); }

__global__ __launch_bounds__(512, 4) void qlin4_kernel(
    const float* __restrict__ x,      // [8, 8192]
    const int*   __restrict__ qw,     // [8192, 4096] values 0..255
    const float* __restrict__ scale,  // [8192, 64]
    const float* __restrict__ zero,   // [8192, 64]
    float*       __restrict__ out)    // [8, 8192] (pre-zeroed; atomicAdd)
{
    extern __shared__ float4 xs[];    // 4096 slots = 64KB, swizzled

    const int tid  = threadIdx.x;
    const int lane = tid & 63;
    const int wave = tid >> 6;
    const int bid  = blockIdx.x;
    const int ks   = bid >> 8;                    // 0..3
    const int n0   = (bid & 255) * ROWS + wave * RPW;

    const float4* __restrict__ x4  = reinterpret_cast<const float4*>(x);
    const int4*   __restrict__ qw4 = reinterpret_cast<const int4*>(qw);

    // ---- stage x K-slice into LDS: physical slot P holds logical S = swz(P).
    #pragma unroll
    for (int rho = 0; rho < 8; ++rho) {
        const int P = rho * 512 + tid;
        const int S = swz(P);                     // involution
        xs[P] = x4[(S >> 9) * (INF / 4) + ks * (KSLICE / 4) + (S & 511)];
    }

    // ---- per-wave scale/zero*scale preload: lane (r<<4|g) = row n0+r, group g.
    const int r_h = lane >> 4, g_h = lane & 15;
    const float sreg  = scale[(n0 + r_h) * NG + ks * 16 + g_h];
    const float zsreg = zero[(n0 + r_h) * NG + ks * 16 + g_h] * sreg;

    float acc[M][RPW];
    #pragma unroll
    for (int m = 0; m < M; ++m)
        #pragma unroll
        for (int r = 0; r < RPW; ++r) acc[m][r] = 0.0f;

    __syncthreads();

    // ---- prologue: weight chunk t=0
    int4 qc[RPW], qn[RPW];
    #pragma unroll
    for (int r = 0; r < RPW; ++r)
        qc[r] = qw4[(size_t)(n0 + r) * PK4ROW + ks * 256 + lane];

    #pragma unroll 1
    for (int t = 0; t < NIT; ++t) {
        // prefetch next chunk (vmcnt wait lands after this iter's FMA block)
        if (t + 1 < NIT) {
            #pragma unroll
            for (int r = 0; r < RPW; ++r)
                qn[r] = qw4[(size_t)(n0 + r) * PK4ROW + ks * 256 + (t + 1) * 64 + lane];
        }

        // scale / zero*scale for this chunk: group offset = t*4 + (lane>>4)
        float s_v[RPW], zs[RPW];
        #pragma unroll
        for (int r = 0; r < RPW; ++r) {
            const int src = r * 16 + t * 4 + (lane >> 4);
            s_v[r] = __shfl(sreg,  src, 64);
            zs[r]  = __shfl(zsreg, src, 64);
        }

        // ---- half A: packed ints .x/.y -> k = 8*lane+0..3, x slot S (even)
        {
            float w[RPW][4];
            #pragma unroll
            for (int r = 0; r < RPW; ++r) {
                w[r][0] = fmaf((float)(qc[r].x & 15),        s_v[r], -zs[r]);
                w[r][1] = fmaf((float)((qc[r].x >> 4) & 15), s_v[r], -zs[r]);
                w[r][2] = fmaf((float)(qc[r].y & 15),        s_v[r], -zs[r]);
                w[r][3] = fmaf((float)((qc[r].y >> 4) & 15), s_v[r], -zs[r]);
            }
            #pragma unroll
            for (int m = 0; m < M; ++m) {
                const int S = m * 512 + t * 128 + 2 * lane;
                const float4 xa = xs[swz(S)];
                #pragma unroll
                for (int r = 0; r < RPW; ++r) {
                    float a = acc[m][r];
                    a = fmaf(w[r][0], xa.x, a);
                    a = fmaf(w[r][1], xa.y, a);
                    a = fmaf(w[r][2], xa.z, a);
                    a = fmaf(w[r][3], xa.w, a);
                    acc[m][r] = a;
                }
            }
        }

        // ---- half B: packed ints .z/.w -> k = 8*lane+4..7, x slot S+1
        {
            float w[RPW][4];
            #pragma unroll
            for (int r = 0; r < RPW; ++r) {
                w[r][0] = fmaf((float)(qc[r].z & 15),        s_v[r], -zs[r]);
                w[r][1] = fmaf((float)((qc[r].z >> 4) & 15), s_v[r], -zs[r]);
                w[r][2] = fmaf((float)(qc[r].w & 15),        s_v[r], -zs[r]);
                w[r][3] = fmaf((float)((qc[r].w >> 4) & 15), s_v[r], -zs[r]);
            }
            #pragma unroll
            for (int m = 0; m < M; ++m) {
                const int S = m * 512 + t * 128 + 2 * lane + 1;
                const float4 xb = xs[swz(S)];
                #pragma unroll
                for (int r = 0; r < RPW; ++r) {
                    float a = acc[m][r];
                    a = fmaf(w[r][0], xb.x, a);
                    a = fmaf(w[r][1], xb.y, a);
                    a = fmaf(w[r][2], xb.z, a);
                    a = fmaf(w[r][3], xb.w, a);
                    acc[m][r] = a;
                }
            }
        }

        #pragma unroll
        for (int r = 0; r < RPW; ++r) qc[r] = qn[r];
    }

    // ---- wave butterfly reduction; one atomicAdd per (m, r).
    #pragma unroll
    for (int m = 0; m < M; ++m) {
        #pragma unroll
        for (int r = 0; r < RPW; ++r) {
            float v = acc[m][r];
            #pragma unroll
            for (int off = 32; off > 0; off >>= 1)
                v += __shfl_xor(v, off, 64);
            if (lane == 0)
                atomicAdd(&out[m * OUTF + (n0 + r)], v);
        }
    }
}

extern "C" void kernel_launch(void* const* d_in, const int* in_sizes, int n_in,
                              void* d_out, int out_size, void* d_ws, size_t ws_size,
                              hipStream_t stream) {
    const float* x     = (const float*)d_in[0];
    const int*   qw    = (const int*)d_in[1];
    const float* scale = (const float*)d_in[2];
    const float* zero  = (const float*)d_in[3];
    float*       out   = (float*)d_out;

    hipMemsetAsync(out, 0, (size_t)M * OUTF * sizeof(float), stream);

    const int blocks = (OUTF / ROWS) * KS;   // 256 * 4 = 1024
    qlin4_kernel<<<blocks, 512, 65536, stream>>>(x, qw, scale, zero, out);
}

// Round 7
// 51.372 us; speedup vs baseline: 14.3066x; 1.1118x over previous
//
#include <hip/hip_runtime.h>

// out[8,8192] = x[8,8192] @ W^T, W = dequant4(qweight, scale, zero), GROUP=128.
// qweight int32-per-byte (2 nibbles, low=even k), [8192 n][4096 k-dwords].
//
// R7: bf16 MFMA path. Wave owns one 16-col n-tile x 512-k slice (KS=16).
//  - B frag: one int4 load/lane = 4 packed int32 = 8 k (64B/row-quad, full lines).
//    Dequant in f32 (exact magic-int + fma(s,-z*s)), pack bf16 via v_cvt_pk.
//  - A frag: two float4 x loads (lanes with row<8; rows 8..15 zero-padded),
//    pack bf16. A and B use the SAME per-lane k-bijection -> contraction is
//    correct regardless of the HW's internal k slot order.
//  - C layout (HW-verified): col=lane&15, row=(lane>>4)*4+reg -> rows 0..7
//    stored by lanes with (lane>>4)<2 via atomicAdd (KS partial sums).

typedef __attribute__((ext_vector_type(8))) short bf16x8;
typedef __attribute__((ext_vector_type(4))) float f32x4;

constexpr int Mdim  = 8;
constexpr int N     = 8192;
constexpr int K     = 8192;
constexpr int NG    = 64;           // groups per row
constexpr int KS    = 16;           // K splits
constexpr int KSL   = K / KS;       // 512 k per wave slice
constexpr int GPS   = KSL / 128;    // 4 groups per slice
constexpr int ROWI4 = K / 8;        // 1024 int4 per weight row

__device__ __forceinline__ float nib_lo(int q) {
    return __int_as_float((q & 15) | 0x4B000000) - 8388608.0f;      // exact
}
__device__ __forceinline__ float nib_hi(int q) {
    return __int_as_float(((q >> 4) & 15) | 0x4B000000) - 8388608.0f;
}
__device__ __forceinline__ int pkbf(float lo, float hi) {           // 2xf32 -> packed bf16 (RNE)
    int r;
    asm("v_cvt_pk_bf16_f32 %0, %1, %2" : "=v"(r) : "v"(lo), "v"(hi));
    return r;
}

__global__ __launch_bounds__(512, 4) void qmfma_kernel(
    const float* __restrict__ x,      // [8, 8192]
    const int*   __restrict__ qw,     // [8192, 4096]
    const float* __restrict__ scale,  // [8192, 64]
    const float* __restrict__ zero,   // [8192, 64]
    float*       __restrict__ out)    // [8, 8192] pre-zeroed
{
    const int tid  = threadIdx.x;
    const int lane = tid & 63;
    const int wave = tid >> 6;
    const int bid  = blockIdx.x;
    const int ks   = bid >> 6;                    // 0..15
    const int nb   = bid & 63;                    // n-block
    const int n0   = nb * 128 + wave * 16;
    const int nl   = n0 + (lane & 15);            // this lane's B row / C col
    const int kb   = lane >> 4;                   // k-quad 0..3
    const bool mv  = (lane & 15) < Mdim;          // A row exists?

    const int4*   __restrict__ qrow = reinterpret_cast<const int4*>(qw) + (size_t)nl * ROWI4;
    const float4* __restrict__ xrow = reinterpret_cast<const float4*>(x) + (size_t)(lane & 15) * (K / 4);

    f32x4 acc = {0.f, 0.f, 0.f, 0.f};
    const int kbase = ks * KSL;

    // group-scalar prefetch (g=0)
    float s_n = scale[nl * NG + ks * GPS];
    float z_n = zero [nl * NG + ks * GPS];

    #pragma unroll 1
    for (int g = 0; g < GPS; ++g) {
        const float cs  = s_n;
        const float csz = z_n * s_n;
        if (g + 1 < GPS) {
            s_n = scale[nl * NG + ks * GPS + g + 1];
            z_n = zero [nl * NG + ks * GPS + g + 1];
        }
        const int kg = kbase + g * 128;

        #pragma unroll
        for (int t = 0; t < 4; ++t) {
            const int k0 = kg + t * 32;

            // B: 4 packed int32 = 8 k values for (row nl, k = k0 + kb*8 .. +7)
            const int4 qd = qrow[(k0 >> 3) + kb];

            // A: 8 x values, same k range, row = lane&15 (zero for rows 8..15)
            float4 xa = {0.f, 0.f, 0.f, 0.f}, xb = {0.f, 0.f, 0.f, 0.f};
            if (mv) {
                xa = xrow[(k0 >> 2) + kb * 2];
                xb = xrow[(k0 >> 2) + kb * 2 + 1];
            }

            union { int4 u; bf16x8 v; } A, B;
            A.u.x = pkbf(xa.x, xa.y);
            A.u.y = pkbf(xa.z, xa.w);
            A.u.z = pkbf(xb.x, xb.y);
            A.u.w = pkbf(xb.z, xb.w);

            B.u.x = pkbf(fmaf(nib_lo(qd.x), cs, -csz), fmaf(nib_hi(qd.x), cs, -csz));
            B.u.y = pkbf(fmaf(nib_lo(qd.y), cs, -csz), fmaf(nib_hi(qd.y), cs, -csz));
            B.u.z = pkbf(fmaf(nib_lo(qd.z), cs, -csz), fmaf(nib_hi(qd.z), cs, -csz));
            B.u.w = pkbf(fmaf(nib_lo(qd.w), cs, -csz), fmaf(nib_hi(qd.w), cs, -csz));

            acc = __builtin_amdgcn_mfma_f32_16x16x32_bf16(A.v, B.v, acc, 0, 0, 0);
        }
    }

    // C: col = lane&15 (= nl), row = kb*4 + i; only rows 0..7 are real.
    if (kb < 2) {
        #pragma unroll
        for (int i = 0; i < 4; ++i) {
            const int m = kb * 4 + i;
            atomicAdd(&out[(size_t)m * N + nl], acc[i]);
        }
    }
}

extern "C" void kernel_launch(void* const* d_in, const int* in_sizes, int n_in,
                              void* d_out, int out_size, void* d_ws, size_t ws_size,
                              hipStream_t stream) {
    const float* x     = (const float*)d_in[0];
    const int*   qw    = (const int*)d_in[1];
    const float* scale = (const float*)d_in[2];
    const float* zero  = (const float*)d_in[3];
    float*       out   = (float*)d_out;

    hipMemsetAsync(out, 0, (size_t)Mdim * N * sizeof(float), stream);

    const int blocks = (N / 128) * KS;   // 64 * 16 = 1024
    qmfma_kernel<<<blocks, 512, 0, stream>>>(x, qw, scale, zero, out);
}

// Round 8
// 44.596 us; speedup vs baseline: 16.4804x; 1.1519x over previous
//
#include <hip/hip_runtime.h>

// out[8,8192] = x[8,8192] @ W^T, W = dequant4(qweight, scale, zero), GROUP=128.
// qweight: one byte value (0..255) per int32, [8192 n][4096 k-bytes], 2 nibbles
// per byte, low nibble = even k.
//
// R8: two-kernel MFMA path.
//  prep:  A_sw[kk][lane] = bf16x8 A-fragment (rows 8..15 zero) -- built ONCE,
//         so the GEMM never rebuilds the (wave-invariant) A side. 256KB in d_ws.
//  gemm:  wave owns 2 n-tiles (32 cols) x 512-k slice (KS=16). Per (g,t):
//         1 A int4 (coalesced, L2-resident) + 2 B int4 (weights, the only HBM
//         stream). B prefetched one group deep (qn while computing qc).
//         A and B use the same per-lane k-bijection (R7-verified); C layout:
//         col=lane&15, row=(lane>>4)*4+reg, rows 0..7 real.
// R3 lesson: launch_bounds(512,4) caps VGPR at 128 (above the ~110 need).

typedef __attribute__((ext_vector_type(8))) short bf16x8;
typedef __attribute__((ext_vector_type(4))) float f32x4;

constexpr int Mdim  = 8;
constexpr int N     = 8192;
constexpr int K     = 8192;
constexpr int NG    = 64;           // groups per row
constexpr int KS    = 16;           // K splits
constexpr int KSL   = K / KS;       // 512 k per wave slice
constexpr int GPS   = KSL / 128;    // 4 groups per slice
constexpr int ROWI4 = K / 8;        // 1024 int4 per weight row
constexpr int NKK   = K / 32;       // 256 A k-blocks

__device__ __forceinline__ float nib_lo(int q) {
    return __int_as_float((q & 15) | 0x4B000000) - 8388608.0f;      // exact
}
__device__ __forceinline__ float nib_hi(int q) {
    return __int_as_float(((q >> 4) & 15) | 0x4B000000) - 8388608.0f;
}
__device__ __forceinline__ int pkbf(float lo, float hi) {           // 2xf32 -> 2xbf16 (RNE)
    int r;
    asm("v_cvt_pk_bf16_f32 %0, %1, %2" : "=v"(r) : "v"(lo), "v"(hi));
    return r;
}

// ---- prep: x f32 -> per-lane bf16 A fragments. idx = kk*64 + lane.
__global__ __launch_bounds__(256) void prep_kernel(
    const float* __restrict__ x, int4* __restrict__ A_sw)
{
    const int idx = blockIdx.x * 256 + threadIdx.x;   // 0..16383
    const int l   = idx & 63;
    const int kk  = idx >> 6;
    const int row = l & 15;
    const int k0  = kk * 32 + (l >> 4) * 8;           // this lane's 8 k's
    float4 xa = {0.f, 0.f, 0.f, 0.f}, xb = {0.f, 0.f, 0.f, 0.f};
    if (row < Mdim) {
        const float4* xr = reinterpret_cast<const float4*>(x) + (size_t)row * (K / 4);
        xa = xr[k0 / 4];
        xb = xr[k0 / 4 + 1];
    }
    int4 r;
    r.x = pkbf(xa.x, xa.y);
    r.y = pkbf(xa.z, xa.w);
    r.z = pkbf(xb.x, xb.y);
    r.w = pkbf(xb.z, xb.w);
    A_sw[idx] = r;
}

// ---- gemm
__global__ __launch_bounds__(512, 4) void qmfma_kernel(
    const int*   __restrict__ qw,     // [8192, 4096]
    const float* __restrict__ scale,  // [8192, 64]
    const float* __restrict__ zero,   // [8192, 64]
    const int4*  __restrict__ A_sw,   // [256][64]
    float*       __restrict__ out)    // [8, 8192] pre-zeroed
{
    const int lane = threadIdx.x & 63;
    const int wave = threadIdx.x >> 6;
    const int bid  = blockIdx.x;                  // 512 blocks
    const int ks   = bid >> 5;                    // 0..15
    const int nb   = bid & 31;                    // n-block (256 cols)
    const int c0   = nb * 256 + wave * 32;        // wave's first col
    const int nl0  = c0 + (lane & 15);            // tile0 row / C col
    const int nl1  = nl0 + 16;                    // tile1
    const int kb   = lane >> 4;                   // k-quad 0..3

    const int4* __restrict__ qrow0 = reinterpret_cast<const int4*>(qw) + (size_t)nl0 * ROWI4;
    const int4* __restrict__ qrow1 = reinterpret_cast<const int4*>(qw) + (size_t)nl1 * ROWI4;

    f32x4 acc0 = {0.f, 0.f, 0.f, 0.f};
    f32x4 acc1 = {0.f, 0.f, 0.f, 0.f};

    const int g0 = ks * GPS;                      // first group of slice
    const int kq = ks * 64;                       // int4 offset of slice in a row

    // scale/zero prefetch (g = 0)
    float s0 = scale[nl0 * NG + g0], z0 = zero[nl0 * NG + g0];
    float s1 = scale[nl1 * NG + g0], z1 = zero[nl1 * NG + g0];

    // B prefetch (g = 0): 4 t-steps x 2 tiles
    int4 qc0[4], qc1[4], qn0[4], qn1[4];
    #pragma unroll
    for (int t = 0; t < 4; ++t) {
        qc0[t] = qrow0[kq + t * 4 + kb];
        qc1[t] = qrow1[kq + t * 4 + kb];
    }

    #pragma unroll 1
    for (int g = 0; g < GPS; ++g) {
        const float cs0 = s0, csz0 = z0 * s0;
        const float cs1 = s1, csz1 = z1 * s1;

        if (g + 1 < GPS) {
            const int kqn = kq + (g + 1) * 16;
            #pragma unroll
            for (int t = 0; t < 4; ++t) {
                qn0[t] = qrow0[kqn + t * 4 + kb];
                qn1[t] = qrow1[kqn + t * 4 + kb];
            }
            s0 = scale[nl0 * NG + g0 + g + 1]; z0 = zero[nl0 * NG + g0 + g + 1];
            s1 = scale[nl1 * NG + g0 + g + 1]; z1 = zero[nl1 * NG + g0 + g + 1];
        }

        #pragma unroll
        for (int t = 0; t < 4; ++t) {
            // A fragment: one coalesced L2-resident int4
            union { int4 u; bf16x8 v; } A;
            A.u = A_sw[(ks * 16 + g * 4 + t) * 64 + lane];

            union { int4 u; bf16x8 v; } B0, B1;
            const int4 qa = qc0[t];
            B0.u.x = pkbf(fmaf(nib_lo(qa.x), cs0, -csz0), fmaf(nib_hi(qa.x), cs0, -csz0));
            B0.u.y = pkbf(fmaf(nib_lo(qa.y), cs0, -csz0), fmaf(nib_hi(qa.y), cs0, -csz0));
            B0.u.z = pkbf(fmaf(nib_lo(qa.z), cs0, -csz0), fmaf(nib_hi(qa.z), cs0, -csz0));
            B0.u.w = pkbf(fmaf(nib_lo(qa.w), cs0, -csz0), fmaf(nib_hi(qa.w), cs0, -csz0));
            const int4 qb = qc1[t];
            B1.u.x = pkbf(fmaf(nib_lo(qb.x), cs1, -csz1), fmaf(nib_hi(qb.x), cs1, -csz1));
            B1.u.y = pkbf(fmaf(nib_lo(qb.y), cs1, -csz1), fmaf(nib_hi(qb.y), cs1, -csz1));
            B1.u.z = pkbf(fmaf(nib_lo(qb.z), cs1, -csz1), fmaf(nib_hi(qb.z), cs1, -csz1));
            B1.u.w = pkbf(fmaf(nib_lo(qb.w), cs1, -csz1), fmaf(nib_hi(qb.w), cs1, -csz1));

            acc0 = __builtin_amdgcn_mfma_f32_16x16x32_bf16(A.v, B0.v, acc0, 0, 0, 0);
            acc1 = __builtin_amdgcn_mfma_f32_16x16x32_bf16(A.v, B1.v, acc1, 0, 0, 0);
        }

        #pragma unroll
        for (int t = 0; t < 4; ++t) { qc0[t] = qn0[t]; qc1[t] = qn1[t]; }
    }

    // C: col = lane&15, row = kb*4 + i; rows 0..7 real -> kb < 2 stores.
    if (kb < 2) {
        #pragma unroll
        for (int i = 0; i < 4; ++i) {
            const int m = kb * 4 + i;
            atomicAdd(&out[(size_t)m * N + nl0], acc0[i]);
            atomicAdd(&out[(size_t)m * N + nl1], acc1[i]);
        }
    }
}

extern "C" void kernel_launch(void* const* d_in, const int* in_sizes, int n_in,
                              void* d_out, int out_size, void* d_ws, size_t ws_size,
                              hipStream_t stream) {
    const float* x     = (const float*)d_in[0];
    const int*   qw    = (const int*)d_in[1];
    const float* scale = (const float*)d_in[2];
    const float* zero  = (const float*)d_in[3];
    float*       out   = (float*)d_out;
    int4*        A_sw  = (int4*)d_ws;             // 256KB

    hipMemsetAsync(out, 0, (size_t)Mdim * N * sizeof(float), stream);
    prep_kernel<<<NKK * 64 / 256, 256, 0, stream>>>(x, A_sw);
    qmfma_kernel<<<(N / 256) * KS, 512, 0, stream>>>(qw, scale, zero, A_sw, out);
}

// Round 9
// 40.744 us; speedup vs baseline: 18.0385x; 1.0945x over previous
//
#include <hip/hip_runtime.h>

// out[8,8192] = x[8,8192] @ W^T, W = dequant4(qweight, scale, zero), GROUP=128.
// qweight: one byte value (0..255) per int32, [8192 n][4096 k-bytes], 2 nibbles
// per byte, low nibble = even k.
//
// R9: two-kernel MFMA path, latency-parallelism round.
//  prep:  A_sw[kk][lane] = bf16x8 A-fragment (rows 8..15 zero), built once.
//  gemm:  KS=32 -> 1024 blocks (4 blocks/CU; VGPR<=64 => 32 waves/CU).
//         Block stages its A slice (8KB) into LDS once; in-loop A = ds_read
//         (lgkmcnt) so vmcnt carries ONLY the B weight stream (2 int4/t,
//         prefetched one group deep). C layout: col=lane&15, row=kb*4+i.

typedef __attribute__((ext_vector_type(8))) short bf16x8;
typedef __attribute__((ext_vector_type(4))) float f32x4;

constexpr int Mdim  = 8;
constexpr int N     = 8192;
constexpr int K     = 8192;
constexpr int NG    = 64;           // groups per row
constexpr int KS    = 32;           // K splits
constexpr int KSL   = K / KS;       // 256 k per wave slice
constexpr int GPS   = KSL / 128;    // 2 groups per slice
constexpr int ROWI4 = K / 8;        // 1024 int4 per weight row
constexpr int NKK   = K / 32;       // 256 A k-blocks
constexpr int SLKK  = KSL / 32;     // 8 A k-blocks per slice

__device__ __forceinline__ float nib_lo(int q) {
    return __int_as_float((q & 15) | 0x4B000000) - 8388608.0f;      // exact
}
__device__ __forceinline__ float nib_hi(int q) {
    return __int_as_float(((q >> 4) & 15) | 0x4B000000) - 8388608.0f;
}
__device__ __forceinline__ int pkbf(float lo, float hi) {           // 2xf32 -> 2xbf16 (RNE)
    int r;
    asm("v_cvt_pk_bf16_f32 %0, %1, %2" : "=v"(r) : "v"(lo), "v"(hi));
    return r;
}

// ---- prep: x f32 -> per-lane bf16 A fragments. idx = kk*64 + lane.
__global__ __launch_bounds__(256) void prep_kernel(
    const float* __restrict__ x, int4* __restrict__ A_sw)
{
    const int idx = blockIdx.x * 256 + threadIdx.x;   // 0..16383
    const int l   = idx & 63;
    const int kk  = idx >> 6;
    const int row = l & 15;
    const int k0  = kk * 32 + (l >> 4) * 8;           // this lane's 8 k's
    float4 xa = {0.f, 0.f, 0.f, 0.f}, xb = {0.f, 0.f, 0.f, 0.f};
    if (row < Mdim) {
        const float4* xr = reinterpret_cast<const float4*>(x) + (size_t)row * (K / 4);
        xa = xr[k0 / 4];
        xb = xr[k0 / 4 + 1];
    }
    int4 r;
    r.x = pkbf(xa.x, xa.y);
    r.y = pkbf(xa.z, xa.w);
    r.z = pkbf(xb.x, xb.y);
    r.w = pkbf(xb.z, xb.w);
    A_sw[idx] = r;
}

// ---- gemm
__global__ __launch_bounds__(512, 4) void qmfma_kernel(
    const int*   __restrict__ qw,     // [8192, 4096]
    const float* __restrict__ scale,  // [8192, 64]
    const float* __restrict__ zero,   // [8192, 64]
    const int4*  __restrict__ A_sw,   // [256][64]
    float*       __restrict__ out)    // [8, 8192] pre-zeroed
{
    __shared__ int4 As[SLKK * 64];                // 8KB: this slice's A frags

    const int tid  = threadIdx.x;
    const int lane = tid & 63;
    const int wave = tid >> 6;
    const int bid  = blockIdx.x;                  // 1024 blocks
    const int ks   = bid >> 5;                    // 0..31
    const int nb   = bid & 31;                    // n-block (256 cols)
    const int c0   = nb * 256 + wave * 32;        // wave's first col
    const int nl0  = c0 + (lane & 15);            // tile0 row / C col
    const int nl1  = nl0 + 16;                    // tile1
    const int kb   = lane >> 4;                   // k-quad 0..3

    // stage this slice's A fragments: 512 int4 = one per thread
    As[tid] = A_sw[(ks * SLKK) * 64 + tid];

    const int4* __restrict__ qrow0 = reinterpret_cast<const int4*>(qw) + (size_t)nl0 * ROWI4;
    const int4* __restrict__ qrow1 = reinterpret_cast<const int4*>(qw) + (size_t)nl1 * ROWI4;

    f32x4 acc0 = {0.f, 0.f, 0.f, 0.f};
    f32x4 acc1 = {0.f, 0.f, 0.f, 0.f};

    const int g0 = ks * GPS;                      // first group of slice
    const int kq = ks * (KSL / 8);                // int4 offset of slice in a row

    // scale/zero prefetch (g = 0)
    float s0 = scale[nl0 * NG + g0], z0 = zero[nl0 * NG + g0];
    float s1 = scale[nl1 * NG + g0], z1 = zero[nl1 * NG + g0];

    // B prefetch (g = 0): 4 t-steps x 2 tiles
    int4 qc0[4], qc1[4], qn0[4], qn1[4];
    #pragma unroll
    for (int t = 0; t < 4; ++t) {
        qc0[t] = qrow0[kq + t * 4 + kb];
        qc1[t] = qrow1[kq + t * 4 + kb];
    }

    __syncthreads();

    #pragma unroll 1
    for (int g = 0; g < GPS; ++g) {
        const float cs0 = s0, csz0 = z0 * s0;
        const float cs1 = s1, csz1 = z1 * s1;

        if (g + 1 < GPS) {
            const int kqn = kq + (g + 1) * 16;
            #pragma unroll
            for (int t = 0; t < 4; ++t) {
                qn0[t] = qrow0[kqn + t * 4 + kb];
                qn1[t] = qrow1[kqn + t * 4 + kb];
            }
            s0 = scale[nl0 * NG + g0 + g + 1]; z0 = zero[nl0 * NG + g0 + g + 1];
            s1 = scale[nl1 * NG + g0 + g + 1]; z1 = zero[nl1 * NG + g0 + g + 1];
        }

        #pragma unroll
        for (int t = 0; t < 4; ++t) {
            // A fragment from LDS (ds_read_b128, conflict-free stride-1)
            union { int4 u; bf16x8 v; } A;
            A.u = As[(g * 4 + t) * 64 + lane];

            union { int4 u; bf16x8 v; } B0, B1;
            const int4 qa = qc0[t];
            B0.u.x = pkbf(fmaf(nib_lo(qa.x), cs0, -csz0), fmaf(nib_hi(qa.x), cs0, -csz0));
            B0.u.y = pkbf(fmaf(nib_lo(qa.y), cs0, -csz0), fmaf(nib_hi(qa.y), cs0, -csz0));
            B0.u.z = pkbf(fmaf(nib_lo(qa.z), cs0, -csz0), fmaf(nib_hi(qa.z), cs0, -csz0));
            B0.u.w = pkbf(fmaf(nib_lo(qa.w), cs0, -csz0), fmaf(nib_hi(qa.w), cs0, -csz0));
            const int4 qb = qc1[t];
            B1.u.x = pkbf(fmaf(nib_lo(qb.x), cs1, -csz1), fmaf(nib_hi(qb.x), cs1, -csz1));
            B1.u.y = pkbf(fmaf(nib_lo(qb.y), cs1, -csz1), fmaf(nib_hi(qb.y), cs1, -csz1));
            B1.u.z = pkbf(fmaf(nib_lo(qb.z), cs1, -csz1), fmaf(nib_hi(qb.z), cs1, -csz1));
            B1.u.w = pkbf(fmaf(nib_lo(qb.w), cs1, -csz1), fmaf(nib_hi(qb.w), cs1, -csz1));

            acc0 = __builtin_amdgcn_mfma_f32_16x16x32_bf16(A.v, B0.v, acc0, 0, 0, 0);
            acc1 = __builtin_amdgcn_mfma_f32_16x16x32_bf16(A.v, B1.v, acc1, 0, 0, 0);
        }

        #pragma unroll
        for (int t = 0; t < 4; ++t) { qc0[t] = qn0[t]; qc1[t] = qn1[t]; }
    }

    // C: col = lane&15, row = kb*4 + i; rows 0..7 real -> kb < 2 stores.
    if (kb < 2) {
        #pragma unroll
        for (int i = 0; i < 4; ++i) {
            const int m = kb * 4 + i;
            atomicAdd(&out[(size_t)m * N + nl0], acc0[i]);
            atomicAdd(&out[(size_t)m * N + nl1], acc1[i]);
        }
    }
}

extern "C" void kernel_launch(void* const* d_in, const int* in_sizes, int n_in,
                              void* d_out, int out_size, void* d_ws, size_t ws_size,
                              hipStream_t stream) {
    const float* x     = (const float*)d_in[0];
    const int*   qw    = (const int*)d_in[1];
    const float* scale = (const float*)d_in[2];
    const float* zero  = (const float*)d_in[3];
    float*       out   = (float*)d_out;
    int4*        A_sw  = (int4*)d_ws;             // 256KB

    hipMemsetAsync(out, 0, (size_t)Mdim * N * sizeof(float), stream);
    prep_kernel<<<NKK * 64 / 256, 256, 0, stream>>>(x, A_sw);
    qmfma_kernel<<<(N / 256) * KS, 512, 0, stream>>>(qw, scale, zero, A_sw, out);
}